// Round 4
// baseline (736.587 us; speedup 1.0000x reference)
//
#include <hip/hip_runtime.h>

// F2FConv3d on MI355X.
// contrib = X·W as f16 MFMA (16x16x32) into 9 PER-K-BASIS f32 accumulators, bary folded
// in the f32 epilogue (zero VALU between MFMAs; no x*bary B-build, no bary f16 convert).
// K ordering: p = kbasis*64 + i (chunk c of 32: kbasis = c>>1, i = (c&1)*32 + [0,32)).
// Wave w owns output channels [w*16, w*16+16): A-frags = 18 x half8 = 72 AGPRs + 72 AGPR accs.
//
// V5: (a) acc-per-k scheme above; (b) __launch_bounds__(256,2) + GRID1=512 -> residency
//     GUARANTEED (2 blocks/CU: 39KB LDS, <=256 regs/wave) which enables (c) fused BN:
//     device-scope done-counter spin replaces pass3 (each block normalizes its own OUT
//     slice, L2/L3-warm). Staging pipeline unchanged from V4: 2 groups per parity,
//     global_load_lds direct, depth-2 counted vmcnt (steady vmcnt(9), never 0 in loop),
//     raw s_barrier, X XOR-swizzled via pre-swizzled global src (linear LDS dest).
//
// D layout (measured, m89): row = quad*4 + reg (channel), col = lane&15 (texture)
//   -> facet (4 consecutive textures) = shfl_xor 1,2 across lanes.

typedef _Float16 half8  __attribute__((ext_vector_type(8)));
typedef _Float16 h2     __attribute__((ext_vector_type(2)));
typedef __fp16   fp16x2 __attribute__((ext_vector_type(2)));
typedef float    f32x4  __attribute__((ext_vector_type(4)));
typedef float    f32x2  __attribute__((ext_vector_type(2)));

#define NGROUPS 100000   // 1.6M textures / 16 per group
#define NPAIRS  50000    // groups staged in pairs (8KB X contiguous)
#define FFACETS 400000
#define GRID1   512      // 2 blocks/CU x 256 CUs, residency guaranteed by launch bounds
#define LDSP    9472     // per parity: X[0,8192) | BARY[8192,9344) | NTEX[9344,9376)

#define WAITV(N) asm volatile("s_waitcnt vmcnt(" #N ")" ::: "memory")
#define WAITL0() asm volatile("s_waitcnt lgkmcnt(0)" ::: "memory")
#define FENCE()  asm volatile("" ::: "memory")
#define SB0()    __builtin_amdgcn_sched_barrier(0)

union H8 { h2 h[4]; half8 v; };

static __device__ __forceinline__ h2 pkrtz(float a, float b) {
    fp16x2 r = __builtin_amdgcn_cvt_pkrtz(a, b);
    return __builtin_bit_cast(h2, r);
}

static __device__ __forceinline__ void gload16(const void* g, void* l) {
    __builtin_amdgcn_global_load_lds((const __attribute__((address_space(1))) void*)g,
                                     (__attribute__((address_space(3))) void*)l, 16, 0, 0);
}

// ---- kernel 1: swizzle W (fp32 [64][64][9]) -> f16 fragment order in ws, zero stats+flag
__global__ __launch_bounds__(256) void prep_kernel(const float* __restrict__ W,
                                                   _Float16* __restrict__ wswz,
                                                   float* __restrict__ stats) {
    int idx = blockIdx.x * 256 + threadIdx.x;
    if (idx < 36864) {
        int j    = idx & 7;
        int lane = (idx >> 3) & 63;
        int mt   = (idx >> 9) & 3;        // which wave (channel tile)
        int c    = idx >> 11;             // K chunk 0..17
        int o    = mt * 16 + (lane & 15);
        int i    = (c & 1) * 32 + ((lane >> 4) << 3) + j;
        int kb   = c >> 1;
        wswz[idx] = (_Float16)W[(o * 64 + i) * 9 + kb];
    }
    if (idx < 132) stats[idx] = 0.0f;     // 128 stats + done flag (+pad)
}

// ---- kernel 2: fused GEMM + facet mean + bias + ReLU + BN stats + BN normalize
__global__ __launch_bounds__(256, 2) void pass1_kernel(
    const float* __restrict__ X, const float* __restrict__ BARY,
    const _Float16* __restrict__ WSWZ, const float* __restrict__ BIAS,
    const int* __restrict__ NTEX, float* __restrict__ OUT,
    float* __restrict__ stats, const float* __restrict__ GAMMA,
    const float* __restrict__ BETA) {

    __shared__ __align__(16) char lds[2][LDSP];
    __shared__ float sl_s[64];
    __shared__ float sl_s2[64];

    const int tid  = threadIdx.x;
    const int wave = tid >> 6;
    const int lane = tid & 63;
    const int col  = lane & 15;   // texture within group / MFMA column
    const int quad = lane >> 4;

    // A-operand: this wave's 16 output channels, all K. 72 AGPRs, resident whole kernel.
    half8 wf[18];
#pragma unroll
    for (int c = 0; c < 18; ++c)
        wf[c] = *(const half8*)(WSWZ + ((size_t)(c * 4 + wave) * 64 + lane) * 8);

    // bias for this lane's 4 channels: ch = wave*16 + quad*4 + r
    const f32x4 biasv = *(const f32x4*)(BIAS + wave * 16 + quad * 4);

    // ---- stage-side per-thread constants (linear LDS dest, pre-swizzled global src)
    const int pphys  = (wave << 10) + (lane << 4);           // X dst byte within a 4KB half
    const int xsoff  = pphys ^ (((pphys >> 8) & 7) << 4);    // inverse-swizzled global byte off
    const char* Xb   = (const char*)X;
    const char* BAb  = (const char*)BARY;
    const char* NTb  = (const char*)NTEX;

    // ---- read-side per-thread constants (swizzled X addresses; conflict-free b128)
    const int m    = (col & 7) << 4;
    const int a00  = (col << 8) + ((quad << 5) ^ m);
    const int a10  = (col << 8) + (((quad << 5) | 16) ^ m);
    const int bco  = 8192 + col * 36;                        // stride 36B: conflict-free
    const int nco  = 9344 + ((col >> 2) << 2);

    float sacc[4]  = {0.f, 0.f, 0.f, 0.f};
    float s2acc[4] = {0.f, 0.f, 0.f, 0.f};

    const int b = blockIdx.x;
    const int n = (NPAIRS - 1 - b) / GRID1 + 1;              // pairs for this block (uniform)

    // 5 vmem ops per wave per STAGE (uniform across waves)
    auto STAGE = [&](int p, int u) {
        const char* xs = Xb + (size_t)u * 8192;
        gload16(xs + xsoff,        &lds[p][pphys]);
        gload16(xs + 4096 + xsoff, &lds[p][4096 + pphys]);
        gload16(BAb + (size_t)u * 1152 + lane * 16, &lds[p][8192 + lane * 16]);
        if (lane < 8) gload16(BAb + (size_t)u * 1152 + 1024 + lane * 16, &lds[p][9216 + lane * 16]);
        if (lane < 2) gload16(NTb + (size_t)u * 32 + lane * 16,          &lds[p][9344 + lane * 16]);
    };

    auto EPI = [&](f32x4 acc, float rc, int f) {
        f32x4 vv;
#pragma unroll
        for (int r = 0; r < 4; ++r) {
            float s = acc[r];
            s += __shfl_xor(s, 1);
            s += __shfl_xor(s, 2);
            s = s * rc + biasv[r];
            s = s > 0.f ? s : 0.f;
            vv[r] = s;
            sacc[r]  += s;         // every lane in the col-group holds same value:
            s2acc[r] += s * s;     // 4x overcount, corrected by 0.25 at the end
        }
        if ((col & 3) == 0)
            *(f32x4*)(OUT + (size_t)f * 64 + wave * 16 + quad * 4) = vv;
    };

    auto ITER = [&](int p, int u, int upre, bool do_stage) {
        __builtin_amdgcn_s_barrier();          // caller did WAITV: stage(u) landed for all waves
        FENCE();
        const char* L = lds[p];
        // ---- LDS reads for both groups (8x b128 swizzled + 18x b32 + 2x b32)
        f32x4 r0[4], r1[4];
        r0[0] = *(const f32x4*)(L + a00);
        r0[1] = *(const f32x4*)(L + a10);
        r0[2] = *(const f32x4*)(L + a00 + 128);
        r0[3] = *(const f32x4*)(L + a10 + 128);
        r1[0] = *(const f32x4*)(L + 4096 + a00);
        r1[1] = *(const f32x4*)(L + 4096 + a10);
        r1[2] = *(const f32x4*)(L + 4096 + a00 + 128);
        r1[3] = *(const f32x4*)(L + 4096 + a10 + 128);
        float bF0[9], bF1[9];
#pragma unroll
        for (int k = 0; k < 9; ++k) bF0[k] = *(const float*)(L + bco + k * 4);
#pragma unroll
        for (int k = 0; k < 9; ++k) bF1[k] = *(const float*)(L + bco + 576 + k * 4);
        const int nt0 = *(const int*)(L + nco);
        const int nt1 = *(const int*)(L + nco + 16);

        // ---- pack X to f16 once per group-half (B-operands built ONCE, reused 9x)
        H8 xlo0, xhi0, xlo1, xhi1;
        xlo0.h[0] = pkrtz(r0[0][0], r0[0][1]);  xlo0.h[1] = pkrtz(r0[0][2], r0[0][3]);
        xlo0.h[2] = pkrtz(r0[1][0], r0[1][1]);  xlo0.h[3] = pkrtz(r0[1][2], r0[1][3]);
        xhi0.h[0] = pkrtz(r0[2][0], r0[2][1]);  xhi0.h[1] = pkrtz(r0[2][2], r0[2][3]);
        xhi0.h[2] = pkrtz(r0[3][0], r0[3][1]);  xhi0.h[3] = pkrtz(r0[3][2], r0[3][3]);
        xlo1.h[0] = pkrtz(r1[0][0], r1[0][1]);  xlo1.h[1] = pkrtz(r1[0][2], r1[0][3]);
        xlo1.h[2] = pkrtz(r1[1][0], r1[1][1]);  xlo1.h[3] = pkrtz(r1[1][2], r1[1][3]);
        xhi1.h[0] = pkrtz(r1[2][0], r1[2][1]);  xhi1.h[1] = pkrtz(r1[2][2], r1[2][3]);
        xhi1.h[2] = pkrtz(r1[3][0], r1[3][1]);  xhi1.h[3] = pkrtz(r1[3][2], r1[3][3]);
        const float rc0 = __builtin_amdgcn_rcpf((float)nt0);   // exact for pow2 counts
        const float rc1 = __builtin_amdgcn_rcpf((float)nt1);

        WAITL0();                              // all reads of buf p done before overwrite
        SB0();
        __builtin_amdgcn_s_barrier();          // all waves finished reading buf p
        FENCE();
        if (do_stage) STAGE(p, upre);          // pair u+2: flies across the next 2 iterations
        FENCE();                               // pin stage before stores in vmcnt queue order

        // ---- 36 MFMAs, pure (zero VALU interleave); 9 per-k accumulators per group
        f32x4 acc0[9], acc1[9];
#pragma unroll
        for (int k = 0; k < 9; ++k) { acc0[k] = (f32x4){0,0,0,0}; acc1[k] = (f32x4){0,0,0,0}; }
        __builtin_amdgcn_s_setprio(1);
#pragma unroll
        for (int kb = 0; kb < 9; ++kb) {
            acc0[kb] = __builtin_amdgcn_mfma_f32_16x16x32_f16(wf[2 * kb],     xlo0.v, acc0[kb], 0, 0, 0);
            acc1[kb] = __builtin_amdgcn_mfma_f32_16x16x32_f16(wf[2 * kb],     xlo1.v, acc1[kb], 0, 0, 0);
            acc0[kb] = __builtin_amdgcn_mfma_f32_16x16x32_f16(wf[2 * kb + 1], xhi0.v, acc0[kb], 0, 0, 0);
            acc1[kb] = __builtin_amdgcn_mfma_f32_16x16x32_f16(wf[2 * kb + 1], xhi1.v, acc1[kb], 0, 0, 0);
        }
        __builtin_amdgcn_s_setprio(0);

        // ---- fold bary in f32 (9 FMA per output elem), then mean/bias/ReLU/stats/store
        f32x4 accA, accB;
#pragma unroll
        for (int r = 0; r < 4; ++r) {
            float sA = bF0[0] * acc0[0][r];
            float sB = bF1[0] * acc1[0][r];
#pragma unroll
            for (int k = 1; k < 9; ++k) {
                sA = __builtin_fmaf(bF0[k], acc0[k][r], sA);
                sB = __builtin_fmaf(bF1[k], acc1[k][r], sB);
            }
            accA[r] = sA; accB[r] = sB;
        }
        const int f0 = u * 8 + (col >> 2);
        EPI(accA, rc0, f0);
        EPI(accB, rc1, f0 + 4);
    };

    // ---- software pipeline: depth-2 pairs, counted vmcnt
    // per-iter vmem queue per wave: [stage:5][stores:2] -> steady wait = 2+5+2 = 9
    STAGE(0, b);
    STAGE(1, b + GRID1);
    WAITV(5); ITER(0, b,         b + 2 * GRID1, true);   // also drains wf prologue loads
    WAITV(7); ITER(1, b + GRID1, b + 3 * GRID1, true);
    int t = 2;
    for (; t < n - 2; ++t) {
        WAITV(9);
        ITER(t & 1, b + t * GRID1, b + (t + 2) * GRID1, true);
    }
    WAITV(9); ITER(t & 1, b + t * GRID1, 0, false); ++t;   // t = n-2
    WAITV(4); ITER(t & 1, b + t * GRID1, 0, false);        // t = n-1

    // reduce stats across the 16 cols; channels partitioned by (wave,quad,r)
#pragma unroll
    for (int r = 0; r < 4; ++r) {
        float s = sacc[r], s2 = s2acc[r];
        s  += __shfl_xor(s, 1);  s  += __shfl_xor(s, 2);
        s  += __shfl_xor(s, 4);  s  += __shfl_xor(s, 8);
        s2 += __shfl_xor(s2, 1); s2 += __shfl_xor(s2, 2);
        s2 += __shfl_xor(s2, 4); s2 += __shfl_xor(s2, 8);
        if (col == 0) {
            sl_s [wave * 16 + quad * 4 + r] = s  * 0.25f;
            sl_s2[wave * 16 + quad * 4 + r] = s2 * 0.25f;
        }
    }
    __syncthreads();
    if (tid < 64)        atomicAdd(&stats[tid],      sl_s [tid]);
    else if (tid < 128)  atomicAdd(&stats[tid],      sl_s2[tid - 64]);

    // ---- fused BN normalize: device-scope spin barrier (residency guaranteed: 2 blk/CU)
    int* done = (int*)(stats + 128);
    WAITV(0);                                  // this wave's OUT stores + stats atomics done
    __syncthreads();                           // all waves of the block drained
    if (tid == 0) {
        __hip_atomic_fetch_add(done, 1, __ATOMIC_RELEASE, __HIP_MEMORY_SCOPE_AGENT);
        int spins = 0;
        while (__hip_atomic_load(done, __ATOMIC_ACQUIRE, __HIP_MEMORY_SCOPE_AGENT) < GRID1
               && spins < (1 << 30)) { ++spins; __builtin_amdgcn_s_sleep(8); }
    }
    __syncthreads();

    const int ch0 = (tid * 2) & 63;            // even; ch1 = ch0+1
    const float invF = 1.0f / (float)FFACETS;
    float s1a = __hip_atomic_load(&stats[ch0],      __ATOMIC_RELAXED, __HIP_MEMORY_SCOPE_AGENT);
    float s2a = __hip_atomic_load(&stats[64 + ch0], __ATOMIC_RELAXED, __HIP_MEMORY_SCOPE_AGENT);
    float s1b = __hip_atomic_load(&stats[ch0 + 1],      __ATOMIC_RELAXED, __HIP_MEMORY_SCOPE_AGENT);
    float s2b = __hip_atomic_load(&stats[64 + ch0 + 1], __ATOMIC_RELAXED, __HIP_MEMORY_SCOPE_AGENT);
    float mu0 = s1a * invF, va0 = s2a * invF - mu0 * mu0;
    float mu1 = s1b * invF, va1 = s2b * invF - mu1 * mu1;
    float sc0 = rsqrtf(va0 + 1e-3f) * GAMMA[ch0], be0 = BETA[ch0];
    float sc1 = rsqrtf(va1 + 1e-3f) * GAMMA[ch0 + 1], be1 = BETA[ch0 + 1];

    // normalize this block's own OUT slice (pairs u = b, b+GRID1, ...; 512 f32 per pair)
    for (int u = b; u < NPAIRS; u += GRID1) {
        float* p = OUT + (size_t)u * 512 + tid * 2;
        f32x2 v = *(f32x2*)p;
        v[0] = (v[0] - mu0) * sc0 + be0;
        v[1] = (v[1] - mu1) * sc1 + be1;
        *(f32x2*)p = v;
    }
}

extern "C" void kernel_launch(void* const* d_in, const int* in_sizes, int n_in,
                              void* d_out, int out_size, void* d_ws, size_t ws_size,
                              hipStream_t stream) {
    const float* X     = (const float*)d_in[0];
    const float* BARY  = (const float*)d_in[1];
    const float* W     = (const float*)d_in[2];
    const float* BIAS  = (const float*)d_in[3];
    const float* GAMMA = (const float*)d_in[4];
    const float* BETA  = (const float*)d_in[5];
    const int*   NTEX  = (const int*)d_in[6];
    float* OUT = (float*)d_out;

    _Float16* wswz = (_Float16*)d_ws;                       // 73728 B
    float* stats   = (float*)((char*)d_ws + 73728);         // 128 stats + done flag

    prep_kernel<<<144, 256, 0, stream>>>(W, wswz, stats);
    pass1_kernel<<<GRID1, 256, 0, stream>>>(X, BARY, wswz, BIAS, NTEX, OUT, stats, GAMMA, BETA);
}

// Round 5
// 665.957 us; speedup vs baseline: 1.1061x; 1.1061x over previous
//
#include <hip/hip_runtime.h>

// F2FConv3d on MI355X.
// contrib = (x ⊗ bary) @ Wflat  as f16 MFMA (16x16x32), W = A-operand in registers (AGPRs).
// K ordering: p = kbasis*64 + i  (chunk c of 32: kbasis = c>>1, i = (c&1)*32 + [0,32)).
// Wave w owns output channels [w*16, w*16+16): A-frags = 18 x half8 = 72 regs, loaded once.
//
// V6 = V4 skeleton (2 groups per buffer, depth-2 counted vmcnt, never 0 in loop) with:
//  (a) READ-LINEAR X LDS layout: read j of half h = lds + h*4096 + j*1024 + lane*16
//      (canonical conflict-free b128). The permutation lives entirely in the per-lane
//      GLOBAL source of global_load_lds: wave w, lane l sources
//      (l&15)*256 + (l>>4)*32 + (w&1)*16 + (w>>1)*128 (+h*4096). Fixes the measured
//      6.4M SQ_LDS_BANK_CONFLICT (old XOR swizzle used only 8 bank slots) and
//      reduces read addressing to one base reg + immediate offsets.
//  (b) SINGLE barrier per iteration via 3-buffer rotation: stage(t) targets the buffer
//      read at t-1; every wave's reads are consumed (lgkm drained) before it reaches
//      the next barrier, so no second barrier / explicit lgkm drain needed.
//      vmcnt ladder: per-iter queue = [stage:5][stores:2], steady WAITV(9).
//
// D layout (measured, m89): row = quad*4 + reg (channel), col = lane&15 (texture)
//   -> facet (4 consecutive textures) = shfl_xor 1,2 across lanes.

typedef _Float16 half8  __attribute__((ext_vector_type(8)));
typedef _Float16 h2     __attribute__((ext_vector_type(2)));
typedef __fp16   fp16x2 __attribute__((ext_vector_type(2)));
typedef float    f32x4  __attribute__((ext_vector_type(4)));

#define NGROUPS 100000   // 1.6M textures / 16 per group
#define NPAIRS  50000    // groups staged in pairs (8KB X contiguous)
#define FFACETS 400000
#define GRID1   768      // 3 blocks/CU x 256 CUs, exactly resident
#define LDSP    9472     // per buffer: X[0,8192) | BARY[8192,9344) | NTEX[9344,9376)

#define WAITV(N) asm volatile("s_waitcnt vmcnt(" #N ")" ::: "memory")
#define FENCE()  asm volatile("" ::: "memory")

union H8 { h2 h[4]; half8 v; };

static __device__ __forceinline__ h2 pkrtz(float a, float b) {
    fp16x2 r = __builtin_amdgcn_cvt_pkrtz(a, b);
    return __builtin_bit_cast(h2, r);
}

static __device__ __forceinline__ void gload16(const void* g, void* l) {
    __builtin_amdgcn_global_load_lds((const __attribute__((address_space(1))) void*)g,
                                     (__attribute__((address_space(3))) void*)l, 16, 0, 0);
}

// ---- kernel 1: swizzle W (fp32 [64][64][9]) -> f16 fragment order in ws, zero stats
__global__ __launch_bounds__(256) void prep_kernel(const float* __restrict__ W,
                                                   _Float16* __restrict__ wswz,
                                                   float* __restrict__ stats) {
    int idx = blockIdx.x * 256 + threadIdx.x;
    if (idx < 36864) {
        int j    = idx & 7;
        int lane = (idx >> 3) & 63;
        int mt   = (idx >> 9) & 3;        // which wave (channel tile)
        int c    = idx >> 11;             // K chunk 0..17
        int o    = mt * 16 + (lane & 15);
        int i    = (c & 1) * 32 + ((lane >> 4) << 3) + j;
        int kb   = c >> 1;
        wswz[idx] = (_Float16)W[(o * 64 + i) * 9 + kb];
    }
    if (idx < 128) stats[idx] = 0.0f;
}

// ---- kernel 2: fused GEMM + facet mean + bias + ReLU + BN-stat accumulation
__global__ __launch_bounds__(256, 3) void pass1_kernel(
    const float* __restrict__ X, const float* __restrict__ BARY,
    const _Float16* __restrict__ WSWZ, const float* __restrict__ BIAS,
    const int* __restrict__ NTEX, float* __restrict__ OUT,
    float* __restrict__ stats) {

    __shared__ __align__(16) char ldsbuf[3 * LDSP];
    __shared__ float sl_s[64];
    __shared__ float sl_s2[64];

    const int tid  = threadIdx.x;
    const int wave = tid >> 6;
    const int lane = tid & 63;
    const int col  = lane & 15;   // texture within group / MFMA column
    const int quad = lane >> 4;

    // A-operand: this wave's 16 output channels, all K. 72 regs (AGPRs), resident whole kernel.
    half8 wf[18];
#pragma unroll
    for (int c = 0; c < 18; ++c)
        wf[c] = *(const half8*)(WSWZ + ((size_t)(c * 4 + wave) * 64 + lane) * 8);

    // bias for this lane's 4 channels: ch = wave*16 + quad*4 + r
    const f32x4 biasv = *(const f32x4*)(BIAS + wave * 16 + quad * 4);

    // ---- stage-side constants: linear LDS dest, permuted per-lane global src
    const int xdst = (wave << 10) + (lane << 4);             // dest byte within a 4KB half
    const int xsrc = ((lane & 15) << 8) + ((lane >> 4) << 5) // texture row + channel quad
                   + ((wave & 1) << 4) + ((wave >> 1) << 7); // wave covers (j&1)*16+(j>>1)*128
    const char* Xb  = (const char*)X;
    const char* BAb = (const char*)BARY;
    const char* NTb = (const char*)NTEX;

    // ---- read-side constants: X reads are lane-linear (conflict-free b128)
    const int xrd = lane << 4;
    const int bco = 8192 + col * 36;                         // 16 distinct banks, 4-way bcast
    const int nco = 9344 + ((col >> 2) << 2);

    float sacc[4]  = {0.f, 0.f, 0.f, 0.f};
    float s2acc[4] = {0.f, 0.f, 0.f, 0.f};

    const int b = blockIdx.x;
    const int n = (NPAIRS - 1 - b) / GRID1 + 1;              // pairs for this block (uniform)

    // 5 vmem ops per wave per STAGE (uniform across waves)
    auto STAGE = [&](char* S, int u) {
        const char* xs = Xb + (size_t)u * 8192;
        FENCE();
        gload16(xs + xsrc,        S + xdst);
        gload16(xs + 4096 + xsrc, S + 4096 + xdst);
        gload16(BAb + (size_t)u * 1152 + lane * 16, S + 8192 + lane * 16);
        if (lane < 8) gload16(BAb + (size_t)u * 1152 + 1024 + lane * 16, S + 9216 + lane * 16);
        if (lane < 2) gload16(NTb + (size_t)u * 32 + lane * 16,          S + 9344 + lane * 16);
        FENCE();
    };

    auto EPI = [&](f32x4 acc, float rc, int f) {
        f32x4 vv;
#pragma unroll
        for (int r = 0; r < 4; ++r) {
            float s = acc[r];
            s += __shfl_xor(s, 1);
            s += __shfl_xor(s, 2);
            s = s * rc + biasv[r];
            s = s > 0.f ? s : 0.f;
            vv[r] = s;
            sacc[r]  += s;         // every lane in the col-group holds same value:
            s2acc[r] += s * s;     // 4x overcount, corrected by 0.25 at the end
        }
        if ((col & 3) == 0)
            *(f32x4*)(OUT + (size_t)f * 64 + wave * 16 + quad * 4) = vv;
    };

    // ITER: [barrier][read buf L][stage into S][pack f16][36 MFMA][epilogue+stores]
    // Safety of single barrier: every wave consumes its ds_reads (lgkm drained) before
    // reaching the NEXT barrier, and S at iter t is the buffer read at t-1.
    auto ITER = [&](const char* L, char* S, int u, int upre, bool do_stage) {
        __builtin_amdgcn_s_barrier();          // caller did WAITV: stage(u) landed for all waves
        FENCE();
        // ---- LDS reads: 8x b128 lane-linear + 18x b32 bcast + 2x b32
        f32x4 r0[4], r1[4];
#pragma unroll
        for (int j = 0; j < 4; ++j) {
            r0[j] = *(const f32x4*)(L + (j << 10) + xrd);
            r1[j] = *(const f32x4*)(L + 4096 + (j << 10) + xrd);
        }
        float bF0[9], bF1[9];
#pragma unroll
        for (int k = 0; k < 9; ++k) bF0[k] = *(const float*)(L + bco + k * 4);
#pragma unroll
        for (int k = 0; k < 9; ++k) bF1[k] = *(const float*)(L + bco + 576 + k * 4);
        const int nt0 = *(const int*)(L + nco);
        const int nt1 = *(const int*)(L + nco + 16);

        if (do_stage) STAGE(S, upre);          // issued early; flies across 2 iterations

        // ---- convert current tiles to f16
        h2 xh0[8], xh1[8], bh0[9], bh1[9];
        xh0[0] = pkrtz(r0[0][0], r0[0][1]);  xh0[1] = pkrtz(r0[0][2], r0[0][3]);
        xh0[2] = pkrtz(r0[1][0], r0[1][1]);  xh0[3] = pkrtz(r0[1][2], r0[1][3]);
        xh0[4] = pkrtz(r0[2][0], r0[2][1]);  xh0[5] = pkrtz(r0[2][2], r0[2][3]);
        xh0[6] = pkrtz(r0[3][0], r0[3][1]);  xh0[7] = pkrtz(r0[3][2], r0[3][3]);
        xh1[0] = pkrtz(r1[0][0], r1[0][1]);  xh1[1] = pkrtz(r1[0][2], r1[0][3]);
        xh1[2] = pkrtz(r1[1][0], r1[1][1]);  xh1[3] = pkrtz(r1[1][2], r1[1][3]);
        xh1[4] = pkrtz(r1[2][0], r1[2][1]);  xh1[5] = pkrtz(r1[2][2], r1[2][3]);
        xh1[6] = pkrtz(r1[3][0], r1[3][1]);  xh1[7] = pkrtz(r1[3][2], r1[3][3]);
#pragma unroll
        for (int k = 0; k < 9; ++k) { bh0[k] = pkrtz(bF0[k], bF0[k]); bh1[k] = pkrtz(bF1[k], bF1[k]); }
        const float rc0 = __builtin_amdgcn_rcpf((float)nt0);   // exact for pow2 counts
        const float rc1 = __builtin_amdgcn_rcpf((float)nt1);

        // ---- 36 MFMAs as two independent 18-chains (g0/g1 interleaved)
        f32x4 accA = {0.f, 0.f, 0.f, 0.f};
        f32x4 accB = {0.f, 0.f, 0.f, 0.f};
        __builtin_amdgcn_s_setprio(1);
#pragma unroll
        for (int c = 0; c < 18; ++c) {
            const int hh = (c & 1) * 4;
            const h2 bkA = bh0[c >> 1];
            const h2 bkB = bh1[c >> 1];
            H8 fa, fb;
            fa.h[0] = xh0[hh + 0] * bkA;  fa.h[1] = xh0[hh + 1] * bkA;
            fa.h[2] = xh0[hh + 2] * bkA;  fa.h[3] = xh0[hh + 3] * bkA;
            accA = __builtin_amdgcn_mfma_f32_16x16x32_f16(wf[c], fa.v, accA, 0, 0, 0);
            fb.h[0] = xh1[hh + 0] * bkB;  fb.h[1] = xh1[hh + 1] * bkB;
            fb.h[2] = xh1[hh + 2] * bkB;  fb.h[3] = xh1[hh + 3] * bkB;
            accB = __builtin_amdgcn_mfma_f32_16x16x32_f16(wf[c], fb.v, accB, 0, 0, 0);
        }
        __builtin_amdgcn_s_setprio(0);

        // ---- facet mean + bias + ReLU + stats + store (facet = 4 adjacent lanes)
        const int f0 = u * 8 + (col >> 2);
        EPI(accA, rc0, f0);
        EPI(accB, rc1, f0 + 4);
    };

    char* B0 = ldsbuf;
    char* B1 = ldsbuf + LDSP;
    char* B2 = ldsbuf + 2 * LDSP;

    // ---- software pipeline: 3-buffer rotation, stage(t) -> buffer read at t-1
    STAGE(B0, b);
    STAGE(B1, b + GRID1);
    WAITV(5); ITER(B0, B2, b,         b + 2 * GRID1, true);   // also drains wf prologue loads
    WAITV(7); ITER(B1, B0, b + GRID1, b + 3 * GRID1, true);
    char *rd = B2, *st = B1, *ot = B0;
    int t = 2;
    for (; t < n - 2; ++t) {
        WAITV(9);
        ITER(rd, st, b + t * GRID1, b + (t + 2) * GRID1, true);
        char* tmp = ot; ot = st; st = rd; rd = tmp;
    }
    WAITV(9); ITER(rd, st, b + t * GRID1, 0, false);
    { char* tmp = ot; ot = st; st = rd; rd = tmp; } ++t;
    WAITV(4); ITER(rd, st, b + t * GRID1, 0, false);

    // reduce stats across the 16 cols; channels partitioned by (wave,quad,r)
#pragma unroll
    for (int r = 0; r < 4; ++r) {
        float s = sacc[r], s2 = s2acc[r];
        s  += __shfl_xor(s, 1);  s  += __shfl_xor(s, 2);
        s  += __shfl_xor(s, 4);  s  += __shfl_xor(s, 8);
        s2 += __shfl_xor(s2, 1); s2 += __shfl_xor(s2, 2);
        s2 += __shfl_xor(s2, 4); s2 += __shfl_xor(s2, 8);
        if (col == 0) {
            sl_s [wave * 16 + quad * 4 + r] = s  * 0.25f;
            sl_s2[wave * 16 + quad * 4 + r] = s2 * 0.25f;
        }
    }
    __syncthreads();
    if (tid < 64)        atomicAdd(&stats[tid],      sl_s [tid]);
    else if (tid < 128)  atomicAdd(&stats[tid],      sl_s2[tid - 64]);
}

// ---- kernel 3: in-place batch-norm normalize on OUT
__global__ __launch_bounds__(256) void pass3_kernel(float* __restrict__ OUT,
    const float* __restrict__ stats, const float* __restrict__ gamma,
    const float* __restrict__ beta) {
    const int tid = threadIdx.x;
    const size_t l = (size_t)blockIdx.x * 256 + tid;
    const int c0 = ((int)l & 15) * 4;     // grid*256 is a multiple of 16 -> constant per thread
    float mu[4], sc[4], be[4];
    const float invF = 1.0f / (float)FFACETS;
#pragma unroll
    for (int u = 0; u < 4; ++u) {
        int ch = c0 + u;
        float m  = stats[ch] * invF;
        float va = stats[64 + ch] * invF - m * m;
        mu[u] = m;
        sc[u] = rsqrtf(va + 1e-3f) * gamma[ch];
        be[u] = beta[ch];
    }
    const size_t n4 = (size_t)FFACETS * 16;
    for (size_t i = l; i < n4; i += (size_t)gridDim.x * 256) {
        f32x4 v = ((f32x4*)OUT)[i];
#pragma unroll
        for (int u = 0; u < 4; ++u)
            v[u] = (v[u] - mu[u]) * sc[u] + be[u];
        ((f32x4*)OUT)[i] = v;
    }
}

extern "C" void kernel_launch(void* const* d_in, const int* in_sizes, int n_in,
                              void* d_out, int out_size, void* d_ws, size_t ws_size,
                              hipStream_t stream) {
    const float* X     = (const float*)d_in[0];
    const float* BARY  = (const float*)d_in[1];
    const float* W     = (const float*)d_in[2];
    const float* BIAS  = (const float*)d_in[3];
    const float* GAMMA = (const float*)d_in[4];
    const float* BETA  = (const float*)d_in[5];
    const int*   NTEX  = (const int*)d_in[6];
    float* OUT = (float*)d_out;

    _Float16* wswz = (_Float16*)d_ws;                       // 73728 B
    float* stats   = (float*)((char*)d_ws + 73728);         // 128 floats

    prep_kernel<<<144, 256, 0, stream>>>(W, wswz, stats);
    pass1_kernel<<<GRID1, 256, 0, stream>>>(X, BARY, wswz, BIAS, NTEX, OUT, stats);
    pass3_kernel<<<2048, 256, 0, stream>>>(OUT, stats, GAMMA, BETA);
}